// Round 3
// baseline (164.280 us; speedup 1.0000x reference)
//
#include <hip/hip_runtime.h>
#include <cstdint>
#include <cstddef>

typedef __bf16 bf16_t;
typedef __bf16 bf16x8 __attribute__((ext_vector_type(8)));
typedef __bf16 bf16x4 __attribute__((ext_vector_type(4)));
typedef float f32x4 __attribute__((ext_vector_type(4)));

#define N_SEQ 2048
#define BATCH 2
#define EMB   1024
#define HID   1024
#define NHEAD 16
#define HDIM  64
#define NBROW (N_SEQ * BATCH)   /* 4096 GEMM rows (n*B+b) */
#define ATT_SCALE2 (0.03125f * 1.44269504f)  /* 1/sqrt(1024) * log2(e) */

#define EXP2F(x) __builtin_amdgcn_exp2f(x)   /* __exp2f collides with glibc macro */

static __device__ __forceinline__ void async_copy16(const bf16_t* g, bf16_t* l) {
  __builtin_amdgcn_global_load_lds((const __attribute__((address_space(1))) void*)g,
                                   (__attribute__((address_space(3))) void*)l,
                                   16, 0, 0);
}

// ---------------- fused prep: convert x + transpose both weights -----------
__global__ __launch_bounds__(256) void prep_kernel(
    const float* __restrict__ x, const float* __restrict__ Wp,
    const float* __restrict__ Wo, bf16_t* __restrict__ Xb,
    bf16_t* __restrict__ Wpt, bf16_t* __restrict__ Wot) {
  int bid = blockIdx.x;
  if (bid < 4096) {
    int i = (bid * 256 + threadIdx.x) * 4;
    float4 v = *(const float4*)(x + i);
    bf16x4 o;
    o[0] = (bf16_t)v.x; o[1] = (bf16_t)v.y; o[2] = (bf16_t)v.z; o[3] = (bf16_t)v.w;
    *(bf16x4*)(Xb + i) = o;
    return;
  }
  __shared__ float tile[32][33];
  const float* in; bf16_t* out; int R, C, bx;
  if (bid < 4096 + 3072) { bx = bid - 4096; in = Wp; out = Wpt; R = 1024; C = 3072; }
  else                   { bx = bid - 7168; in = Wo; out = Wot; R = 1024; C = 1024; }
  int gx = C / 32;
  int bc = (bx % gx) * 32, br = (bx / gx) * 32;
  int tx = threadIdx.x & 31, ty = threadIdx.x >> 5;   // 32 x 8
  #pragma unroll
  for (int i = 0; i < 32; i += 8)
    tile[ty + i][tx] = in[(size_t)(br + ty + i) * C + bc + tx];
  __syncthreads();
  #pragma unroll
  for (int i = 0; i < 32; i += 8)
    out[(size_t)(bc + ty + i) * R + br + tx] = (bf16_t)tile[tx][ty + i];
}

// ---------------- deep-pipelined 256x256 GEMM (QKV) ------------------------
// 8 waves (2M x 4N), per-wave C = 128x64. K split into half-steps of 32.
// FOUR LDS buffers (A 16KB + B 16KB each = 128KB total), prefetch distance 3.
// Main loop NEVER drains vmcnt to 0: raw s_barrier + counted s_waitcnt
// vmcnt(8) (oldest tile's 4 loads were issued 3 iterations ago).
// Safety: a wave at barrier s+1 has drained its tile-s ds_reads (lgkm before
// MFMA), so stage(s+4) into buf[s&3] issued after that barrier cannot race.
// Swizzle (4-octet rows): LDS[row][sl] holds K-octet sl^((row>>1)&3); read
// slot = (quad^(row>>1))&3 -> a wave's frag read covers 16 full 64B rows,
// zero bank conflicts.
template <bool SCALEQ, bool WRITE_VT>
__global__ __launch_bounds__(512, 2) void gemm8p_kernel(
    const bf16_t* __restrict__ A, const bf16_t* __restrict__ Bt,
    const float* __restrict__ bias, bf16_t* __restrict__ Cout,
    bf16_t* __restrict__ Vt, int Nn, int K) {
  constexpr int BM = 256, BN = 256;
  __shared__ __align__(16) bf16_t sm[4 * 16384];   // 128 KB
  int tid = threadIdx.x;
  int wave = tid >> 6, lane = tid & 63;
  int c = lane & 15, quad = lane >> 4;
  int bm = blockIdx.x * BM, bn = blockIdx.y * BN;
  int wm = (wave >> 2) * 128;     // 0 / 128
  int wn = (wave & 3) * 64;       // 0 / 64 / 128 / 192

  f32x4 acc[8][4] = {};

  // staging descriptors: chunk p = i*512 + tid; row = p>>2 (4 chunks/row)
  const bf16_t* agp[2]; const bf16_t* bgp[2]; int aldo[2];
  #pragma unroll
  for (int i = 0; i < 2; ++i) {
    int p = i * 512 + tid;
    int row = p >> 2;
    int ko = (p & 3) ^ ((row >> 1) & 3);
    agp[i] = A + (size_t)(bm + row) * K + ko * 8;
    bgp[i] = Bt + (size_t)(bn + row) * K + ko * 8;
    aldo[i] = (i * 512 + wave * 64) * 8;    // elems within one 8192-elem buffer
  }

  auto stage = [&](int s) {
    int q = s & 3, ks = s * 32;
    bf16_t* ab = sm + q * 16384;
    bf16_t* bb = ab + 8192;
    #pragma unroll
    for (int i = 0; i < 2; ++i) {
      async_copy16(agp[i] + ks, ab + aldo[i]);
      async_copy16(bgp[i] + ks, bb + aldo[i]);
    }
  };

  auto compute = [&](int s) {
    int q = s & 3;
    const bf16_t* ab = sm + q * 16384;
    const bf16_t* bb = ab + 8192;
    bf16x8 af[8], bfr[4];
    #pragma unroll
    for (int mt = 0; mt < 8; ++mt) {
      int row = wm + mt * 16 + c;
      int slot = (quad ^ (row >> 1)) & 3;
      af[mt] = *(const bf16x8*)(ab + row * 32 + slot * 8);
    }
    #pragma unroll
    for (int nt = 0; nt < 4; ++nt) {
      int row = wn + nt * 16 + c;
      int slot = (quad ^ (row >> 1)) & 3;
      bfr[nt] = *(const bf16x8*)(bb + row * 32 + slot * 8);
    }
    __builtin_amdgcn_s_setprio(1);
    #pragma unroll
    for (int mt = 0; mt < 8; ++mt)
      #pragma unroll
      for (int nt = 0; nt < 4; ++nt)
        acc[mt][nt] = __builtin_amdgcn_mfma_f32_16x16x32_bf16(
            af[mt], bfr[nt], acc[mt][nt], 0, 0, 0);
    __builtin_amdgcn_s_setprio(0);
  };

  int nHK = K / 32;                 // 32 half-steps
  stage(0); stage(1); stage(2);
  for (int s = 0; s < nHK - 3; ++s) {
    asm volatile("s_waitcnt vmcnt(8)" ::: "memory");   // tile s landed
    __builtin_amdgcn_s_barrier();
    asm volatile("" ::: "memory");
    stage(s + 3);                   // into buf[(s+3)&3]: freed by this barrier
    compute(s);
  }
  asm volatile("s_waitcnt vmcnt(8)" ::: "memory");
  __builtin_amdgcn_s_barrier();
  asm volatile("" ::: "memory");
  compute(nHK - 3);
  asm volatile("s_waitcnt vmcnt(4)" ::: "memory");
  __builtin_amdgcn_s_barrier();
  asm volatile("" ::: "memory");
  compute(nHK - 2);
  asm volatile("s_waitcnt vmcnt(0)" ::: "memory");
  __builtin_amdgcn_s_barrier();
  asm volatile("" ::: "memory");
  compute(nHK - 1);

  // ---- C write (bias + Q-scale), layout identical to verified kernel ----
  #pragma unroll
  for (int nt = 0; nt < 4; ++nt) {
    int col = bn + wn + nt * 16 + c;
    float bv = bias[col];
    float sc = (SCALEQ && col < HID) ? ATT_SCALE2 : 1.0f;
    #pragma unroll
    for (int mt = 0; mt < 8; ++mt)
      #pragma unroll
      for (int r = 0; r < 4; ++r) {
        int loc = wm + mt * 16 + quad * 4 + r;
        float v = (acc[mt][nt][r] + bv) * sc;
        Cout[(size_t)(bm + loc) * Nn + col] = (bf16_t)v;
      }
  }

  // ---- V^T emission: tile spans 4 heads; two passes over batch b --------
  if (WRITE_VT && (bn >= 2 * HID)) {
    int h0 = (bn - 2 * HID) >> 6;
    #pragma unroll
    for (int pass = 0; pass < 2; ++pass) {
      asm volatile("" ::: "memory");
      __builtin_amdgcn_s_barrier();     // K-loop reads / prev pass done
      asm volatile("" ::: "memory");
      #pragma unroll
      for (int nt = 0; nt < 4; ++nt) {
        int dg = wn + nt * 16 + c;      // col within tile [0,256)
        int hh = dg >> 6, dl = dg & 63;
        float bv = bias[bn + dg];
        #pragma unroll
        for (int mt = 0; mt < 8; ++mt)
          #pragma unroll
          for (int r = 0; r < 4; ++r) {
            int loc = wm + mt * 16 + quad * 4 + r;
            if ((loc & 1) == pass)      // batch b == pass
              sm[hh * 8704 + dl * 136 + (loc >> 1)] = (bf16_t)(acc[mt][nt][r] + bv);
          }
      }
      asm volatile("" ::: "memory");
      __builtin_amdgcn_s_barrier();
      asm volatile("" ::: "memory");
      #pragma unroll
      for (int j = 0; j < 8; ++j) {     // 4096 16B-vecs, 8/thread
        int idx = j * 512 + tid;
        int nv = idx & 15;
        int d = (idx >> 4) & 63;
        int hh = idx >> 10;             // 0..3
        bf16x8 vv = *(const bf16x8*)(sm + hh * 8704 + d * 136 + nv * 8);
        *(bf16x8*)(Vt + (size_t)((pass * 16 + h0 + hh) * HDIM + d) * N_SEQ
                   + bm / 2 + nv * 8) = vv;
      }
    }
  }
}

// ---------------- 2-phase GEMM (out-projection): C = A * Bt^T + bias -------
template <int BM, int BN, bool OUT_BF16, bool SCALEQ, bool WRITE_VT>
__global__ __launch_bounds__(256) void gemm_bt_kernel(
    const bf16_t* __restrict__ A, const bf16_t* __restrict__ Bt,
    const float* __restrict__ bias, void* __restrict__ Cout,
    bf16_t* __restrict__ Vt, int M, int Nn, int K) {
  constexpr int BK = 64;
  constexpr int MT = BM / 32;
  constexpr int NT = BN / 32;
  constexpr int CA = BM / 32;
  constexpr int CB = BN / 32;
  constexpr int ASZ = BM * BK;
  constexpr int BSZ = BN * BK;
  __shared__ __align__(16) bf16_t smem[2 * ASZ + 2 * BSZ];
  bf16_t* const Asb = smem;
  bf16_t* const Bsb = smem + 2 * ASZ;
  int tid = threadIdx.x;
  int wave = tid >> 6, lane = tid & 63;
  int c = lane & 15, quad = lane >> 4;
  int bm = blockIdx.x * BM;
  int bn = blockIdx.y * BN;
  int wm = (wave & 1) * (BM / 2), wn = (wave >> 1) * (BN / 2);
  f32x4 acc[MT][NT] = {};

  const bf16_t* agp[CA]; int alo[CA];
  const bf16_t* bgp[CB]; int blo[CB];
  #pragma unroll
  for (int i = 0; i < CA; ++i) {
    int p = i * 256 + tid;
    int row = p >> 3, ko = (p & 7) ^ (row & 7);
    agp[i] = A + (size_t)(bm + row) * K + ko * 8;
    alo[i] = (i * 256 + wave * 64) * 8;
  }
  #pragma unroll
  for (int i = 0; i < CB; ++i) {
    int p = i * 256 + tid;
    int row = p >> 3, ko = (p & 7) ^ (row & 7);
    bgp[i] = Bt + (size_t)(bn + row) * K + ko * 8;
    blo[i] = (i * 256 + wave * 64) * 8;
  }

  #pragma unroll
  for (int i = 0; i < CA; ++i) async_copy16(agp[i], Asb + alo[i]);
  #pragma unroll
  for (int i = 0; i < CB; ++i) async_copy16(bgp[i], Bsb + blo[i]);

  int nkb = K / BK;
  for (int ki = 0; ki < nkb; ++ki) {
    __syncthreads();
    if (ki + 1 < nkb) {
      int kb = (ki + 1) * BK;
      bf16_t* an = Asb + ((ki + 1) & 1) * ASZ;
      bf16_t* bnx = Bsb + ((ki + 1) & 1) * BSZ;
      #pragma unroll
      for (int i = 0; i < CA; ++i) async_copy16(agp[i] + kb, an + alo[i]);
      #pragma unroll
      for (int i = 0; i < CB; ++i) async_copy16(bgp[i] + kb, bnx + blo[i]);
    }
    const bf16_t* as = Asb + (ki & 1) * ASZ;
    const bf16_t* bs = Bsb + (ki & 1) * BSZ;
    #pragma unroll
    for (int kk = 0; kk < 2; ++kk) {
      bf16x8 af[MT], bf[NT];
      #pragma unroll
      for (int mt = 0; mt < MT; ++mt) {
        int row = wm + mt * 16 + c;
        int slot = (kk * 4 + quad) ^ (row & 7);
        af[mt] = *(const bf16x8*)(as + (size_t)(row * 8 + slot) * 8);
      }
      #pragma unroll
      for (int nt = 0; nt < NT; ++nt) {
        int row = wn + nt * 16 + c;
        int slot = (kk * 4 + quad) ^ (row & 7);
        bf[nt] = *(const bf16x8*)(bs + (size_t)(row * 8 + slot) * 8);
      }
      #pragma unroll
      for (int mt = 0; mt < MT; ++mt)
        #pragma unroll
        for (int nt = 0; nt < NT; ++nt)
          acc[mt][nt] = __builtin_amdgcn_mfma_f32_16x16x32_bf16(
              af[mt], bf[nt], acc[mt][nt], 0, 0, 0);
    }
  }

  #pragma unroll
  for (int nt = 0; nt < NT; ++nt) {
    int col = bn + wn + nt * 16 + c;
    float bv = bias[col];
    float sc = (SCALEQ && col < HID) ? ATT_SCALE2 : 1.0f;
    #pragma unroll
    for (int mt = 0; mt < MT; ++mt) {
      #pragma unroll
      for (int r = 0; r < 4; ++r) {
        int loc = wm + mt * 16 + quad * 4 + r;
        int row = bm + loc;
        float v = (acc[mt][nt][r] + bv) * sc;
        if (OUT_BF16)
          ((bf16_t*)Cout)[(size_t)row * Nn + col] = (bf16_t)v;
        else
          ((float*)Cout)[(size_t)row * Nn + col] = v;
      }
    }
  }
}

// ---------------- flash attention (round-1 verified version) ---------------
__global__ __launch_bounds__(512, 4) void flash_attn_kernel(
    const bf16_t* __restrict__ Pj, const bf16_t* __restrict__ Vt,
    bf16_t* __restrict__ AO) {
  __shared__ __align__(16) bf16_t Ks[2][64 * 64];   // [j][d] swizzled
  __shared__ __align__(16) bf16_t Vs[2][64 * 64];   // [d][j] swizzled
  __shared__ __align__(16) bf16_t Ps[8][16 * 64];   // per-wave P[i][j] swizzled
  const int PJP = 3 * HID;
  int tid = threadIdx.x, wave = tid >> 6, lane = tid & 63;
  int c = lane & 15, quad = lane >> 4;
  int c7 = c & 7;
  int bid = blockIdx.x;
  int qb = (bid < 256) ? (15 - (bid >> 5)) : ((bid - 256) >> 5);
  int bh = bid & 31;
  int h = bh & 15, b = bh >> 4;
  int i0 = qb * 128;

  int i_row = i0 + wave * 16 + c;
  const bf16_t* qg = Pj + (size_t)(i_row * BATCH + b) * PJP + h * HDIM + quad * 8;
  bf16x8 qf0 = *(const bf16x8*)(qg);
  bf16x8 qf1 = *(const bf16x8*)(qg + 32);

  f32x4 o[4] = {};                   // O^T: rows d, col i=c
  float lrow = 0.f;

  int jr = tid >> 3, oc = tid & 7;
  int lds_off = jr * 64 + (oc ^ (jr & 7)) * 8;
  const bf16_t* kg0 = Pj + (size_t)b * PJP + HID + h * HDIM + oc * 8;
  const bf16_t* vg0 = Vt + (size_t)(bh * HDIM + jr) * N_SEQ + oc * 8;

  int njt = 2 * qb + 2;
  bf16x8 kreg = *(const bf16x8*)(kg0 + (size_t)jr * BATCH * PJP);
  bf16x8 vreg = *(const bf16x8*)(vg0);

  for (int jt = 0; jt < njt; ++jt) {
    bf16_t* ks = Ks[jt & 1];
    bf16_t* vs = Vs[jt & 1];
    *(bf16x8*)(ks + lds_off) = kreg;
    *(bf16x8*)(vs + lds_off) = vreg;
    __syncthreads();
    if (jt + 1 < njt) {
      int j0n = (jt + 1) * 64;
      kreg = *(const bf16x8*)(kg0 + (size_t)(j0n + jr) * BATCH * PJP);
      vreg = *(const bf16x8*)(vg0 + j0n);
    }

    f32x4 st[4];
    #pragma unroll
    for (int mt = 0; mt < 4; ++mt) {
      const bf16_t* kr = ks + (mt * 16 + c) * 64;
      bf16x8 ka0 = *(const bf16x8*)(kr + ((quad) ^ c7) * 8);
      bf16x8 ka1 = *(const bf16x8*)(kr + ((quad + 4) ^ c7) * 8);
      f32x4 s = {};
      s = __builtin_amdgcn_mfma_f32_16x16x32_bf16(ka0, qf0, s, 0, 0, 0);
      st[mt] = __builtin_amdgcn_mfma_f32_16x16x32_bf16(ka1, qf1, s, 0, 0, 0);
    }
    if (jt >= 2 * qb) {
      int j0 = jt * 64;
      int ig = i0 + wave * 16 + c;
      #pragma unroll
      for (int mt = 0; mt < 4; ++mt)
        #pragma unroll
        for (int r = 0; r < 4; ++r)
          if (j0 + mt * 16 + quad * 4 + r > ig) st[mt][r] = -1e30f;
    }

    #pragma unroll
    for (int mt = 0; mt < 4; ++mt)
      #pragma unroll
      for (int r = 0; r < 4; ++r) {
        st[mt][r] = EXP2F(st[mt][r]);
        lrow += st[mt][r];
      }

    bf16_t* pw = Ps[wave];
    #pragma unroll
    for (int mt = 0; mt < 4; ++mt) {
      bf16x4 pv;
      #pragma unroll
      for (int r = 0; r < 4; ++r) pv[r] = (bf16_t)st[mt][r];
      int joct = mt * 2 + (quad >> 1);
      *(bf16x4*)(pw + c * 64 + (joct ^ c7) * 8 + (quad & 1) * 4) = pv;
    }
    const bf16_t* pr = pw + c * 64;
    bf16x8 pa0 = *(const bf16x8*)(pr + ((quad) ^ c7) * 8);
    bf16x8 pa1 = *(const bf16x8*)(pr + ((quad + 4) ^ c7) * 8);

    #pragma unroll
    for (int nt = 0; nt < 4; ++nt) {
      const bf16_t* vr = vs + (nt * 16 + c) * 64;
      bf16x8 vb0 = *(const bf16x8*)(vr + ((quad) ^ c7) * 8);
      bf16x8 vb1 = *(const bf16x8*)(vr + ((quad + 4) ^ c7) * 8);
      o[nt] = __builtin_amdgcn_mfma_f32_16x16x32_bf16(vb0, pa0, o[nt], 0, 0, 0);
      o[nt] = __builtin_amdgcn_mfma_f32_16x16x32_bf16(vb1, pa1, o[nt], 0, 0, 0);
    }
  }

  float lfull = lrow;
  lfull += __shfl_xor(lfull, 16);
  lfull += __shfl_xor(lfull, 32);
  float linv = 1.0f / lfull;
  int orow = (i0 + wave * 16 + c) * BATCH + b;
  #pragma unroll
  for (int nt = 0; nt < 4; ++nt) {
    bf16x4 pv;
    #pragma unroll
    for (int r = 0; r < 4; ++r) pv[r] = (bf16_t)(o[nt][r] * linv);
    *(bf16x4*)(AO + (size_t)orow * HID + h * HDIM + nt * 16 + quad * 4) = pv;
  }
}

extern "C" void kernel_launch(void* const* d_in, const int* in_sizes, int n_in,
                              void* d_out, int out_size, void* d_ws, size_t ws_size,
                              hipStream_t stream) {
  const float* x      = (const float*)d_in[0];   // [2048][2][1024]
  const float* W_proj = (const float*)d_in[1];   // [1024][3072]
  const float* b_proj = (const float*)d_in[2];   // [3072]
  const float* W_out  = (const float*)d_in[3];   // [1024][1024]
  const float* b_out  = (const float*)d_in[4];   // [1024]

  bf16_t* Xb  = (bf16_t*)d_ws;                               // 4096*1024
  bf16_t* Wpt = Xb  + (size_t)NBROW * EMB;                   // 3072*1024
  bf16_t* Wot = Wpt + (size_t)3 * HID * EMB;                 // 1024*1024
  bf16_t* Pj  = Wot + (size_t)HID * EMB;                     // 4096*3072
  bf16_t* AO  = Pj  + (size_t)NBROW * 3 * HID;               // 4096*1024
  bf16_t* Vt  = AO  + (size_t)NBROW * HID;                   // 32*64*2048

  prep_kernel<<<8192, 256, 0, stream>>>(x, W_proj, W_out, Xb, Wpt, Wot);
  gemm8p_kernel<true, true>
      <<<dim3(NBROW / 256, 3 * HID / 256), 512, 0, stream>>>(
      Xb, Wpt, b_proj, Pj, Vt, 3 * HID, EMB);
  flash_attn_kernel<<<512, 512, 0, stream>>>(Pj, Vt, AO);
  gemm_bt_kernel<128, 128, false, false, false>
      <<<dim3(NBROW / 128, EMB / 128), 256, 0, stream>>>(
      AO, Wot, b_out, d_out, nullptr, NBROW, EMB, HID);
}